// Round 9
// baseline (3921.695 us; speedup 1.0000x reference)
//
#include <hip/hip_runtime.h>
#include <stdint.h>

// Problem constants
#define B_   128
#define T_   256
#define H_   256
#define E_   300
#define G4_  1024   // 4*H

typedef __attribute__((ext_vector_type(8))) short bf16x8s;  // 8 bf16 (4 VGPRs)
typedef __attribute__((ext_vector_type(4))) float f32x4;

__device__ __forceinline__ short f2bf(float f) {
    unsigned u = __builtin_bit_cast(unsigned, f);
    unsigned r = (u + 0x7fffu + ((u >> 16) & 1u)) >> 16;   // RNE
    return (short)r;
}
__device__ __forceinline__ float bf2f(short s) {
    unsigned u = (unsigned)(unsigned short)s;
    return __builtin_bit_cast(float, u << 16);
}
__device__ __forceinline__ float sigm(float x) { return 1.f / (1.f + __expf(-x)); }
__device__ __forceinline__ float ftanh(float x) {
    float e = __expf(-2.f * x);
    return (1.f - e) / (1.f + e);
}

// ---------------- prep: mask dtype detection + mask/rowtok build ----------------
__global__ void k_detect(const unsigned char* __restrict__ m8, int* __restrict__ flag) {
    int i = blockIdx.x * 256 + threadIdx.x;
    if ((i & 3) != 0 && m8[i] != 0) atomicOr(flag, 1);
}

__global__ void k_prep(const void* __restrict__ mask, const int* __restrict__ tokens,
                       const int* __restrict__ flag, float* __restrict__ maskf,
                       int* __restrict__ rowtok) {
    int i = blockIdx.x * 256 + threadIdx.x;      // i = b*T + t
    int isbyte = *flag;
    int mv = isbyte ? (int)((const unsigned char*)mask)[i] : ((const int*)mask)[i];
    maskf[i] = mv ? 1.f : 0.f;
    int b = i >> 8, t = i & 255;
    rowtok[t * B_ + b] = tokens[i];
}

// ---------------- generic W[KREAL][N] -> packed bf16 MFMA B-fragments ----------------
__global__ void k_bpack(const float* __restrict__ W, short* __restrict__ out,
                        int N, int KS, int KREAL) {
    int frag = blockIdx.x;
    int nt = frag / KS, ks = frag - nt * KS;
    int l = threadIdx.x;
    int col = nt * 16 + (l & 15);
    int k0 = ks * 32 + (l >> 4) * 8;
    short tmp[8];
#pragma unroll
    for (int i = 0; i < 8; ++i) {
        int k = k0 + i;
        tmp[i] = (k < KREAL) ? f2bf(W[(size_t)k * N + col]) : (short)0;
    }
    int4 v;
    __builtin_memcpy(&v, tmp, 16);
    ((int4*)out)[(size_t)frag * 64 + l] = v;
}

// ---------------- bf16 MFMA GEMM: C = (A@B + bias) * scale ----------------
// OUTMODE: 0 = fp32 row-major, 1 = bf16 row-major, 2 = LSTM-coop xW fragment layout
//   (mode 2: M = T*128 rows ordered t*128+b, N=1024; fi = ((t*8+gb)*4+q)*16+ln)
template<bool GATHER, bool ABF16, int OUTMODE, int KS>
__global__ __launch_bounds__(256) void k_gemm_mfma(
    const void* __restrict__ Av, const short* __restrict__ Bp,
    const float* __restrict__ bias, void* __restrict__ Cv,
    int N, int KREAL, const int* __restrict__ rowidx, float scale)
{
    constexpr int KP = KS * 32;
    constexpr int LDA = KP + 8;
    __shared__ __align__(16) short As[64 * LDA];
    const int tid = threadIdx.x;
    const int l = tid & 63, w = tid >> 6;
    const int cl = l & 15, rowq = l >> 4;
    const int m0 = blockIdx.x * 64;

    for (int e = tid; e < 64 * KP; e += 256) {
        int r = e / KP, k = e - r * KP;
        int row = m0 + r;
        int arow = GATHER ? rowidx[row] : row;
        short sv = 0;
        if (k < KREAL) {
            if constexpr (ABF16) sv = ((const short*)Av)[(size_t)arow * KREAL + k];
            else                 sv = f2bf(((const float*)Av)[(size_t)arow * KREAL + k]);
        }
        As[r * LDA + k] = sv;
    }
    __syncthreads();

    bf16x8s a[KS];
#pragma unroll
    for (int ks = 0; ks < KS; ++ks)
        a[ks] = *(const bf16x8s*)&As[(w * 16 + cl) * LDA + ks * 32 + rowq * 8];

    const int nchunks = N >> 8;
    for (int ch = 0; ch < nchunks; ++ch) {
#pragma unroll
        for (int ntl = 0; ntl < 16; ++ntl) {
            const int nt = ch * 16 + ntl;
            const float bv = bias[nt * 16 + cl];
            f32x4 y = {bv, bv, bv, bv};
#pragma unroll
            for (int ks = 0; ks < KS; ++ks) {
                bf16x8s bf = *(const bf16x8s*)&Bp[((size_t)(nt * KS + ks) * 64 + l) * 8];
                y = __builtin_amdgcn_mfma_f32_16x16x32_bf16(a[ks], bf, y, 0, 0, 0);
            }
            if constexpr (OUTMODE == 2) {
                const int t  = m0 >> 7;
                const int gb = ((m0 & 127) >> 4) + w;     // batch group 0..7
                const int gg = nt >> 4;                   // gate
                const int q  = (nt & 15) >> 2;            // column-slice block
                const int m  = nt & 3;
                const int ln = gg * 4 + m;                // block-local n-tile
                const size_t fi = (((size_t)t * 8 + gb) * 4 + q) * 16 + ln;
                short4 o;
                o.x = f2bf(y[0] * scale); o.y = f2bf(y[1] * scale);
                o.z = f2bf(y[2] * scale); o.w = f2bf(y[3] * scale);
                *(short4*)&((short*)Cv)[fi * 256 + l * 4] = o;
            } else {
#pragma unroll
                for (int r = 0; r < 4; ++r) {
                    size_t idx = (size_t)(m0 + w * 16 + rowq * 4 + r) * N + nt * 16 + cl;
                    float ov = y[r] * scale;
                    if constexpr (OUTMODE == 1) ((short*)Cv)[idx] = f2bf(ov);
                    else                        ((float*)Cv)[idx] = ov;
                }
            }
        }
    }
}

// ---------------- cooperative LSTM: 8 groups x 4 blocks, LDS-resident Wh slice ----------------
// Group g = blk&7 (XCD-local grouping), q = blk>>3. Block owns h-units [64q, 64q+64)
// for all 4 gates: 16 n-tiles (ln = gg*4+m -> global nt = gg*16 + q*4 + m), all 8 ks in LDS.
// Per step: MFMA from LDS -> ybuf exchange -> activations for own 64 units ->
// h-slice to LDS(own) + global hx (parity dbuf) -> flag release -> spin siblings -> load hb.
__global__ __launch_bounds__(512, 2) void lstm_coop(
    const short* __restrict__ xwp, const short* __restrict__ whp,
    short* __restrict__ hs, short* __restrict__ hx, int* __restrict__ syncf)
{
    __shared__ __align__(16) short whl[128 * 512];   // 128 frags x 1KB = 128 KB
    __shared__ __align__(16) short hb[16 * 264];     // full h (bf16), single-buffered
    __shared__ __align__(16) f32x4 ybuf[16 * 64];    // gate-exchange, 16 KB
    const int tid = threadIdx.x;
    const int l = tid & 63;
    const int w = tid >> 6;            // wave 0..7
    const int cl = l & 15;
    const int rowq = l >> 4;
    const int blk = blockIdx.x;        // 0..31
    const int g = blk & 7;             // batch group (same-XCD siblings)
    const int q = blk >> 3;            // column-slice 0..3

    // stage this block's Wh slice: frag(ln,ks) <- whp frag(gg*16+q*4+m, ks)
    for (int e = tid; e < 128 * 64; e += 512) {       // int4 units
        int fr = e >> 6, lane = e & 63;               // fr = ln*8+ks
        int ln = fr >> 3, ks = fr & 7;
        int gg = ln >> 2, m = ln & 3;
        int gnt = gg * 16 + q * 4 + m;
        ((int4*)whl)[e] = ((const int4*)whp)[(gnt * 8 + ks) * 64 + lane];
    }
    for (int e = tid; e < 16 * 264 / 2; e += 512) ((int*)hb)[e] = 0;

    const int ln0 = w * 2, ln1 = w * 2 + 1;
    const short* xbase = xwp + ((size_t)g * 4 + q) * 4096 + (size_t)l * 4;
    const size_t tstr = 131072;        // 8*4*16*256 shorts per t

    // activation role: jj = tid&63 (h-unit in slice), batches b0 = tid>>6 and b0+8
    const int jj = tid & 63;
    const int am = jj >> 4;
    const int ali = jj & 15;
    const int ab0 = tid >> 6;
    float c0 = 0.f, c1 = 0.f;

    int* myflag = syncf + blk;
    __syncthreads();

    for (int t = 0; t < T_; ++t) {
        // 1. A-fragments from hb (all waves)
        bf16x8s a[8];
#pragma unroll
        for (int ks = 0; ks < 8; ++ks)
            a[ks] = *(const bf16x8s*)&hb[cl * 264 + ks * 32 + rowq * 8];

        // xW for this wave's 2 n-tiles
        const short* xt = xbase + (size_t)t * tstr;
        short4 x0 = *(const short4*)&xt[ln0 * 256];
        short4 x1 = *(const short4*)&xt[ln1 * 256];

        // 2. MFMA (B from LDS)
        f32x4 y0 = {bf2f(x0.x), bf2f(x0.y), bf2f(x0.z), bf2f(x0.w)};
        f32x4 y1 = {bf2f(x1.x), bf2f(x1.y), bf2f(x1.z), bf2f(x1.w)};
#pragma unroll
        for (int ks = 0; ks < 8; ++ks) {
            bf16x8s b0f = *(const bf16x8s*)&whl[((ln0 * 8 + ks) * 64 + l) * 8];
            bf16x8s b1f = *(const bf16x8s*)&whl[((ln1 * 8 + ks) * 64 + l) * 8];
            y0 = __builtin_amdgcn_mfma_f32_16x16x32_bf16(a[ks], b0f, y0, 0, 0, 0);
            y1 = __builtin_amdgcn_mfma_f32_16x16x32_bf16(a[ks], b1f, y1, 0, 0, 0);
        }

        // 3. publish y tiles
        ybuf[ln0 * 64 + l] = y0;
        ybuf[ln1 * 64 + l] = y1;
        __syncthreads();

        // 4. activations for (jj, b0) and (jj, b0+8)
        short* hxw = hx + (size_t)(t & 1) * 32768 + (size_t)blk * 1024;
#pragma unroll
        for (int half = 0; half < 2; ++half) {
            const int b = ab0 + half * 8;
            const int lane_idx = ali + 16 * (b >> 2);
            const int r = b & 3;
            float vi = ybuf[(0 * 4 + am) * 64 + lane_idx][r];
            float vf = ybuf[(1 * 4 + am) * 64 + lane_idx][r];
            float vg = ybuf[(2 * 4 + am) * 64 + lane_idx][r];
            float vo = ybuf[(3 * 4 + am) * 64 + lane_idx][r];
            float iv = sigm(vi), fv = sigm(vf), gv = ftanh(vg), ov = sigm(vo);
            float cprev = half ? c1 : c0;
            float c = fmaf(fv, cprev, iv * gv);
            if (half) c1 = c; else c0 = c;
            float hv = ov * ftanh(c);
            short hvb = f2bf(hv);
            hb[b * 264 + q * 64 + jj] = hvb;
            hxw[b * 64 + jj] = hvb;
            hs[((size_t)(g * 16 + b) * T_ + t) * H_ + q * 64 + jj] = hvb;
        }

        // 5. release own slice, wait for siblings (parity buffer makes overwrite safe)
        __threadfence();
        __syncthreads();
        if (tid == 0)
            __hip_atomic_store(myflag, t + 1, __ATOMIC_RELEASE, __HIP_MEMORY_SCOPE_AGENT);
        if (tid == 64 || tid == 128 || tid == 192) {
            int s = tid >> 6;
            const int* sf = syncf + (((q + s) & 3) * 8 + g);
            while (__hip_atomic_load(sf, __ATOMIC_ACQUIRE, __HIP_MEMORY_SCOPE_AGENT) < t + 1) {}
        }
        __syncthreads();
        __threadfence();

        // 6. gather sibling h-slices into hb
        const short* hxr = hx + (size_t)(t & 1) * 32768;
#pragma unroll
        for (int s = 1; s < 4; ++s) {
            int qq = (q + s) & 3;
            short2 v = *(const short2*)&hxr[(size_t)(qq * 8 + g) * 1024 + tid * 2];
            int e = tid * 2;
            *(short2*)&hb[(e >> 6) * 264 + qq * 64 + (e & 63)] = v;
        }
        __syncthreads();
    }
}

// ---------------- flash-style single-head attention (fp32 q,k,v) ----------------
__global__ __launch_bounds__(256) void k_attn(
    const float* __restrict__ q, const float* __restrict__ kk_,
    const float* __restrict__ v, const float* __restrict__ maskf,
    float* __restrict__ o)
{
    __shared__ __align__(16) float Qs[16][260];
    __shared__ __align__(16) float Ks[16][260];
    __shared__ __align__(16) float Vs[16][260];
    __shared__ float Ss[16][16];
    const int tid = threadIdx.x;
    const int tx = tid & 15, ty = tid >> 4;
    const int b = blockIdx.y, q0 = blockIdx.x * 16;
    const size_t base = (size_t)b * T_ * H_;

    for (int e4 = tid; e4 < 1024; e4 += 256) {
        int r = e4 >> 6, dq = e4 & 63;
        *(float4*)&Qs[r][dq * 4] = *(const float4*)&q[base + (size_t)(q0 + r) * H_ + dq * 4];
    }
    const float mrow = maskf[b * T_ + q0 + ty];
    float m = -1e30f, l = 0.f;
    float acc[16];
#pragma unroll
    for (int i = 0; i < 16; ++i) acc[i] = 0.f;

    for (int kt = 0; kt < 16; ++kt) {
        for (int e4 = tid; e4 < 1024; e4 += 256) {
            int r = e4 >> 6, dq = e4 & 63;
            *(float4*)&Ks[r][dq * 4] = *(const float4*)&kk_[base + (size_t)(kt * 16 + r) * H_ + dq * 4];
            *(float4*)&Vs[r][dq * 4] = *(const float4*)&v  [base + (size_t)(kt * 16 + r) * H_ + dq * 4];
        }
        __syncthreads();
        float s = 0.f;
#pragma unroll 16
        for (int d = 0; d < 256; d += 4) {
            float4 qv = *(const float4*)&Qs[ty][d];
            float4 kv = *(const float4*)&Ks[tx][d];
            s = fmaf(qv.x, kv.x, fmaf(qv.y, kv.y, fmaf(qv.z, kv.z, fmaf(qv.w, kv.w, s))));
        }
        if (mrow == 0.f) s = 0.f;
        Ss[ty][tx] = s;
        __syncthreads();
        float tmax = -1e30f;
#pragma unroll
        for (int x = 0; x < 16; ++x) tmax = fmaxf(tmax, Ss[ty][x]);
        float mnew = fmaxf(m, tmax);
        float rsc = __expf(m - mnew);
        float wv[16], wsum = 0.f;
#pragma unroll
        for (int x = 0; x < 16; ++x) { wv[x] = __expf(Ss[ty][x] - mnew); wsum += wv[x]; }
        l = l * rsc + wsum; m = mnew;
#pragma unroll
        for (int dd = 0; dd < 16; ++dd) acc[dd] *= rsc;
#pragma unroll
        for (int x = 0; x < 16; ++x) {
            float wx = wv[x];
#pragma unroll
            for (int dd = 0; dd < 16; ++dd)
                acc[dd] = fmaf(wx, Vs[x][tx + dd * 16], acc[dd]);
        }
        __syncthreads();
    }
    float inv = 1.f / l;
#pragma unroll
    for (int dd = 0; dd < 16; ++dd)
        o[base + (size_t)(q0 + ty) * H_ + tx + dd * 16] = acc[dd] * inv;
}

// ---------------- FC1 split-K partials ----------------
__global__ __launch_bounds__(256) void k_fc1(
    const float* __restrict__ flat, const float* __restrict__ W1, float* __restrict__ part)
{
    __shared__ __align__(16) float Wt[100][260];
    __shared__ __align__(16) float fs[2][256];
    const int kc = blockIdx.x, tid = threadIdx.x;
    for (int e = tid; e < 25600; e += 256) {
        int k = e / 100, j = e - k * 100;
        Wt[j][k] = W1[(size_t)(kc * 256 + k) * 100 + j];
    }
    __syncthreads();
    const int bh = tid / 100, j = tid - bh * 100;
    for (int bb = 0; bb < 64; ++bb) {
        for (int e = tid; e < 512; e += 256) {
            int bi = e >> 8, k = e & 255;
            fs[bi][k] = flat[(size_t)(bb * 2 + bi) * 65536 + kc * 256 + k];
        }
        __syncthreads();
        if (bh < 2) {
            float acc = 0.f;
#pragma unroll 16
            for (int k = 0; k < 256; k += 4) {
                float4 fv = *(const float4*)&fs[bh][k];
                float4 wv = *(const float4*)&Wt[j][k];
                acc = fmaf(fv.x, wv.x, fmaf(fv.y, wv.y, fmaf(fv.z, wv.z, fmaf(fv.w, wv.w, acc))));
            }
            part[(size_t)kc * 12800 + (bb * 2 + bh) * 100 + j] = acc;
        }
        __syncthreads();
    }
}

// ---------------- head ----------------
__global__ __launch_bounds__(128) void k_head(
    const float* __restrict__ part, const float* __restrict__ b1,
    const float* __restrict__ W2, const float* __restrict__ b2, float* __restrict__ out)
{
    __shared__ float h1s[100];
    __shared__ float ls[2];
    const int b = blockIdx.x, tid = threadIdx.x;
    if (tid < 100) {
        float s = 0.f;
        for (int kc = 0; kc < 256; ++kc) s += part[(size_t)kc * 12800 + b * 100 + tid];
        s += b1[tid];
        h1s[tid] = fmaxf(s, 0.f);
    }
    __syncthreads();
    if (tid < 2) {
        float lg = b2[tid];
        for (int j = 0; j < 100; ++j) lg = fmaf(h1s[j], W2[j * 2 + tid], lg);
        ls[tid] = lg;
    }
    __syncthreads();
    if (tid == 0) {
        float mm = fmaxf(ls[0], ls[1]);
        float e0 = __expf(ls[0] - mm), e1 = __expf(ls[1] - mm);
        float inv = 1.f / (e0 + e1);
        out[b * 2 + 0] = e0 * inv;
        out[b * 2 + 1] = e1 * inv;
    }
}

// ---------------- launch ----------------
extern "C" void kernel_launch(void* const* d_in, const int* in_sizes, int n_in,
                              void* d_out, int out_size, void* d_ws, size_t ws_size,
                              hipStream_t stream) {
    (void)in_sizes; (void)n_in; (void)out_size; (void)ws_size;
    const int*   tokens = (const int*)  d_in[0];
    const void*  mask   =               d_in[1];
    const float* emb    = (const float*)d_in[2];
    const float* Wi     = (const float*)d_in[3];
    const float* Wh     = (const float*)d_in[4];
    const float* b_lstm = (const float*)d_in[5];
    const float* Wq     = (const float*)d_in[6];
    const float* bq     = (const float*)d_in[7];
    const float* Wk     = (const float*)d_in[8];
    const float* bk     = (const float*)d_in[9];
    const float* Wv     = (const float*)d_in[10];
    const float* bv     = (const float*)d_in[11];
    const float* Wo     = (const float*)d_in[12];
    const float* bo     = (const float*)d_in[13];
    const float* W1     = (const float*)d_in[14];
    const float* b1     = (const float*)d_in[15];
    const float* W2     = (const float*)d_in[16];
    const float* b2     = (const float*)d_in[17];
    float* out = (float*)d_out;

    float* ws = (float*)d_ws;
    float* reg0  = ws;                        // 33,554,432 f region (134 MB)
    short* xwp   = (short*)reg0;              // bf16 xW frag layout (67 MB)
    float* hsb   = reg0 + 33554432;           // hs bf16, later attn fp32
    short* hsb16 = (short*)hsb;
    float* maskf = hsb + 8388608;
    int*   rowtok= (int*)(maskf + 32768);
    int*   flag  = rowtok + 32768;
    short* whp   = (short*)((((uintptr_t)(flag + 1)) + 255) & ~(uintptr_t)255);
    short* wip   = whp + 262144;
    short* wqp   = wip + 327680;
    short* wkp   = wqp + 65536;
    short* wvp   = wkp + 65536;
    short* wop   = wvp + 65536;
    short* hx    = wop + 65536;               // 65,536 shorts (parity-dbuf h exchange)
    int*   syncf = (int*)(hx + 65536);        // 32 ints
    // region reuse inside reg0 after LSTM (xwp dead then):
    float* qb   = reg0;
    float* kb   = reg0 + 8388608;
    float* vb   = reg0 + 16777216;
    float* proj = reg0 + 25165824;
    float* attnf = hsb;
    float* part = kb;

    // prep
    hipMemsetAsync(flag, 0, sizeof(int), stream);
    hipMemsetAsync(syncf, 0, 32 * sizeof(int), stream);
    k_detect<<<128, 256, 0, stream>>>((const unsigned char*)mask, flag);
    k_prep<<<128, 256, 0, stream>>>(mask, tokens, flag, maskf, rowtok);

    // weight packs
    k_bpack<<<512, 64, 0, stream>>>(Wh, whp, 1024, 8, 256);
    k_bpack<<<640, 64, 0, stream>>>(Wi, wip, 1024, 10, 300);
    k_bpack<<<128, 64, 0, stream>>>(Wq, wqp, 256, 8, 256);
    k_bpack<<<128, 64, 0, stream>>>(Wk, wkp, 256, 8, 256);
    k_bpack<<<128, 64, 0, stream>>>(Wv, wvp, 256, 8, 256);
    k_bpack<<<128, 64, 0, stream>>>(Wo, wop, 256, 8, 256);

    // xW = gather(emb,tokens) @ Wi + b_lstm -> bf16 in coop fragment layout
    k_gemm_mfma<true, false, 2, 10><<<512, 256, 0, stream>>>(
        emb, wip, b_lstm, xwp, 1024, 300, rowtok, 1.f);

    // LSTM — cooperative, 8 groups x 4 column-slice blocks, LDS-resident Wh
    {
        const short* a0 = xwp; const short* a1 = whp;
        short* a2 = hsb16; short* a3 = hx; int* a4 = syncf;
        void* kargs[] = {&a0, &a1, &a2, &a3, &a4};
        hipLaunchCooperativeKernel((void*)lstm_coop, dim3(32), dim3(512), kargs, 0, stream);
    }

    // q,k,v projections from bf16 hs (q scaled by 1/16)
    k_gemm_mfma<false, true, 0, 8><<<512, 256, 0, stream>>>(
        hsb16, wqp, bq, qb, 256, 256, nullptr, 0.0625f);
    k_gemm_mfma<false, true, 0, 8><<<512, 256, 0, stream>>>(
        hsb16, wkp, bk, kb, 256, 256, nullptr, 1.f);
    k_gemm_mfma<false, true, 0, 8><<<512, 256, 0, stream>>>(
        hsb16, wvp, bv, vb, 256, 256, nullptr, 1.f);

    // attention (writes fp32 over hs region)
    k_attn<<<dim3(16, 128), 256, 0, stream>>>(qb, kb, vb, maskf, attnf);

    // output projection
    k_gemm_mfma<false, false, 0, 8><<<512, 256, 0, stream>>>(
        attnf, wop, bo, proj, 256, 256, nullptr, 1.f);

    // FC1 split-K partials + head
    k_fc1<<<256, 256, 0, stream>>>(proj, W1, part);
    k_head<<<128, 128, 0, stream>>>(part, b1, W2, b2, out);
}

// Round 10
// 1709.895 us; speedup vs baseline: 2.2935x; 2.2935x over previous
//
#include <hip/hip_runtime.h>
#include <stdint.h>

// Problem constants
#define B_   128
#define T_   256
#define H_   256
#define E_   300
#define G4_  1024   // 4*H

typedef __attribute__((ext_vector_type(8))) short bf16x8s;  // 8 bf16 (4 VGPRs)
typedef __attribute__((ext_vector_type(4))) float f32x4;

__device__ __forceinline__ short f2bf(float f) {
    unsigned u = __builtin_bit_cast(unsigned, f);
    unsigned r = (u + 0x7fffu + ((u >> 16) & 1u)) >> 16;   // RNE
    return (short)r;
}
__device__ __forceinline__ float bf2f(short s) {
    unsigned u = (unsigned)(unsigned short)s;
    return __builtin_bit_cast(float, u << 16);
}
__device__ __forceinline__ float sigm(float x) { return 1.f / (1.f + __expf(-x)); }
__device__ __forceinline__ float ftanh(float x) {
    float e = __expf(-2.f * x);
    return (1.f - e) / (1.f + e);
}

// ---------------- prep ----------------
__global__ void k_detect(const unsigned char* __restrict__ m8, int* __restrict__ flag) {
    int i = blockIdx.x * 256 + threadIdx.x;
    if ((i & 3) != 0 && m8[i] != 0) atomicOr(flag, 1);
}

__global__ void k_prep(const void* __restrict__ mask, const int* __restrict__ tokens,
                       const int* __restrict__ flag, float* __restrict__ maskf,
                       int* __restrict__ rowtok) {
    int i = blockIdx.x * 256 + threadIdx.x;      // i = b*T + t
    int isbyte = *flag;
    int mv = isbyte ? (int)((const unsigned char*)mask)[i] : ((const int*)mask)[i];
    maskf[i] = mv ? 1.f : 0.f;
    int b = i >> 8, t = i & 255;
    rowtok[t * B_ + b] = tokens[i];
}

// ---------------- W[KREAL][N] -> packed bf16 MFMA B-fragments ----------------
__global__ void k_bpack(const float* __restrict__ W, short* __restrict__ out,
                        int N, int KS, int KREAL) {
    int frag = blockIdx.x;
    int nt = frag / KS, ks = frag - nt * KS;
    int l = threadIdx.x;
    int col = nt * 16 + (l & 15);
    int k0 = ks * 32 + (l >> 4) * 8;
    short tmp[8];
#pragma unroll
    for (int i = 0; i < 8; ++i) {
        int k = k0 + i;
        tmp[i] = (k < KREAL) ? f2bf(W[(size_t)k * N + col]) : (short)0;
    }
    int4 v;
    __builtin_memcpy(&v, tmp, 16);
    ((int4*)out)[(size_t)frag * 64 + l] = v;
}

// Wq|Wk|Wv (each 256x256) -> one packed frag buffer, nt 0-15=q(scaled 1/16),16-31=k,32-47=v
__global__ void k_packqkv(const float* __restrict__ Wq, const float* __restrict__ Wk,
                          const float* __restrict__ Wv, short* __restrict__ out) {
    int frag = blockIdx.x;              // nt*8+ks, 384 frags
    int nt = frag >> 3, ks = frag & 7;
    int l = threadIdx.x;
    int col = (nt & 15) * 16 + (l & 15);
    int k0 = ks * 32 + (l >> 4) * 8;
    const float* W = nt < 16 ? Wq : (nt < 32 ? Wk : Wv);
    float sc = nt < 16 ? 0.0625f : 1.f;
    short tmp[8];
#pragma unroll
    for (int i = 0; i < 8; ++i) tmp[i] = f2bf(W[(size_t)(k0 + i) * 256 + col] * sc);
    int4 v;
    __builtin_memcpy(&v, tmp, 16);
    ((int4*)out)[(size_t)frag * 64 + l] = v;
}

__global__ void k_bias3(const float* __restrict__ bq, const float* __restrict__ bk,
                        const float* __restrict__ bv, float* __restrict__ bqkv) {
    int i = threadIdx.x;   // 768
    float v;
    if (i < 256) v = bq[i] * 0.0625f;
    else if (i < 512) v = bk[i - 256];
    else v = bv[i - 512];
    bqkv[i] = v;
}

// ---------------- bf16 MFMA GEMM, 128-row blocks, 8 waves ----------------
// OUTMODE: 0 = fp32 row-major; 2 = LSTM xW fragment layout (N=1024, M rows = t*128+b);
//          3 = fused QKV (N=768): q bf16 rm -> Cv, k bf16 rm -> C2, v bf16 TRANSPOSED [B][H][T] -> C3
template<bool GATHER, bool ABF16, int OUTMODE, int KS>
__global__ __launch_bounds__(512) void k_gemm_mfma(
    const void* __restrict__ Av, const short* __restrict__ Bp,
    const float* __restrict__ bias, void* __restrict__ Cv,
    void* __restrict__ C2, void* __restrict__ C3,
    int N, int KREAL, const int* __restrict__ rowidx)
{
    constexpr int KP = KS * 32;
    constexpr int LDA = KP + 8;
    __shared__ __align__(16) short As[128 * LDA];
    const int tid = threadIdx.x;
    const int l = tid & 63, w = tid >> 6;       // wave 0..7
    const int cl = l & 15, rowq = l >> 4;
    const int m0 = blockIdx.x * 128;

    for (int e = tid; e < 128 * KP; e += 512) {
        int r = e / KP, k = e - r * KP;
        int row = m0 + r;
        int arow = GATHER ? rowidx[row] : row;
        short sv = 0;
        if (k < KREAL) {
            if constexpr (ABF16) sv = ((const short*)Av)[(size_t)arow * KREAL + k];
            else                 sv = f2bf(((const float*)Av)[(size_t)arow * KREAL + k]);
        }
        As[r * LDA + k] = sv;
    }
    __syncthreads();

    bf16x8s a[KS];
#pragma unroll
    for (int ks = 0; ks < KS; ++ks)
        a[ks] = *(const bf16x8s*)&As[(w * 16 + cl) * LDA + ks * 32 + rowq * 8];

    const int nchunks = N >> 8;
    for (int ch = 0; ch < nchunks; ++ch) {
#pragma unroll
        for (int ntl = 0; ntl < 16; ++ntl) {
            const int nt = ch * 16 + ntl;
            const float bv = bias[nt * 16 + cl];
            f32x4 y = {bv, bv, bv, bv};
#pragma unroll
            for (int ks = 0; ks < KS; ++ks) {
                bf16x8s bf = *(const bf16x8s*)&Bp[((size_t)(nt * KS + ks) * 64 + l) * 8];
                y = __builtin_amdgcn_mfma_f32_16x16x32_bf16(a[ks], bf, y, 0, 0, 0);
            }
            if constexpr (OUTMODE == 2) {
                // rows = t*128 + b; 128-row block => t = blk, batch-block = wave
                const int t  = m0 >> 7;
                const int wl = (nt >> 1) & 7, pp = nt & 1, gg = nt >> 4;
                const size_t fi = ((((size_t)t * 8 + w) * 8 + wl) * 2 + pp) * 4 + gg;
                short4 o;
                o.x = f2bf(y[0]); o.y = f2bf(y[1]); o.z = f2bf(y[2]); o.w = f2bf(y[3]);
                *(short4*)&((short*)Cv)[fi * 256 + (size_t)l * 4] = o;
            } else if constexpr (OUTMODE == 3) {
                const int gg = nt >> 4;          // 0=q,1=k,2=v
                if (gg < 2) {
                    short* dst = gg ? (short*)C2 : (short*)Cv;
#pragma unroll
                    for (int r = 0; r < 4; ++r) {
                        size_t row = (size_t)m0 + w * 16 + rowq * 4 + r;
                        dst[row * 256 + (nt & 15) * 16 + cl] = f2bf(y[r]);
                    }
                } else {
                    const int bidx = m0 >> 8;
                    const int t0 = (m0 & 255) + w * 16 + rowq * 4;
                    const int d = (nt & 15) * 16 + cl;
                    short4 o;
                    o.x = f2bf(y[0]); o.y = f2bf(y[1]); o.z = f2bf(y[2]); o.w = f2bf(y[3]);
                    *(short4*)&((short*)C3)[((size_t)bidx * 256 + d) * 256 + t0] = o;
                }
            } else {
#pragma unroll
                for (int r = 0; r < 4; ++r) {
                    size_t idx = (size_t)(m0 + w * 16 + rowq * 4 + r) * N + nt * 16 + cl;
                    ((float*)Cv)[idx] = y[r];
                }
            }
        }
    }
}

// ---------------- MFMA LSTM (R7 structure, proven 1220 us) ----------------
#define LDA_H 264

__global__ __launch_bounds__(512, 2) void lstm_mfma(
    const short* __restrict__ xwp, const short* __restrict__ whp,
    short* __restrict__ hs)
{
    __shared__ __align__(16) short whc[128 * 64 * 8];
    __shared__ __align__(16) short hb[2][16 * LDA_H];
    const int tid = threadIdx.x;
    const int l = tid & 63;
    const int w = tid >> 6;
    const int cl = l & 15;
    const int rowq = l >> 4;
    const int bb = blockIdx.x;
    const int bbase = bb * 16;

    for (int e = tid; e < 128 * 64; e += 512) {
        int frag = e >> 6, q = e & 63;
        int nt = frag >> 1, ks = frag & 1;
        ((int4*)whc)[e] = ((const int4*)whp)[(nt * 8 + ks) * 64 + q];
    }
    for (int e = tid; e < 2 * 16 * LDA_H; e += 512) ((short*)hb)[e] = 0;

    bf16x8s wreg[2][4][4];
#pragma unroll
    for (int p = 0; p < 2; ++p)
#pragma unroll
        for (int g = 0; g < 4; ++g)
#pragma unroll
            for (int kr = 0; kr < 4; ++kr) {
                const int nt = g * 16 + w * 2 + p;
                wreg[p][g][kr] = *(const bf16x8s*)&whp[((size_t)(nt * 8 + 2 + kr) * 64 + l) * 8];
            }

    float creg[2][4];
#pragma unroll
    for (int p = 0; p < 2; ++p)
#pragma unroll
        for (int r = 0; r < 4; ++r) creg[p][r] = 0.f;

    const short* xbase = xwp + ((size_t)bb * 8 + w) * 2 * 4 * 256 + (size_t)l * 4;
    const size_t tstride = (size_t)8 * 8 * 2 * 4 * 256;

    auto ld_xw = [&](int t, short4 (&dst)[2][4]) {
        const short* p0 = xbase + (size_t)t * tstride;
#pragma unroll
        for (int p = 0; p < 2; ++p)
#pragma unroll
            for (int g = 0; g < 4; ++g)
                dst[p][g] = *(const short4*)&p0[(p * 4 + g) * 256];
    };

    short4 xwA[2][4], xwB[2][4];
    ld_xw(0, xwA);
    __syncthreads();

    auto step = [&](int t, short4 (&cur)[2][4], short4 (&nxt)[2][4]) {
        ld_xw(t + 1, nxt);

        const short* hbr = hb[t & 1];
        short* hbw = hb[(t + 1) & 1];
        bf16x8s a[8];
#pragma unroll
        for (int ks = 0; ks < 8; ++ks)
            a[ks] = *(const bf16x8s*)&hbr[cl * LDA_H + ks * 32 + rowq * 8];

        f32x4 y[2][4];
#pragma unroll
        for (int p = 0; p < 2; ++p)
#pragma unroll
            for (int g = 0; g < 4; ++g) {
                y[p][g][0] = bf2f(cur[p][g].x);
                y[p][g][1] = bf2f(cur[p][g].y);
                y[p][g][2] = bf2f(cur[p][g].z);
                y[p][g][3] = bf2f(cur[p][g].w);
            }

#pragma unroll
        for (int p = 0; p < 2; ++p) {
#pragma unroll
            for (int g = 0; g < 4; ++g) {
                const int nt = g * 16 + w * 2 + p;
                const size_t sb = ((size_t)nt * 8 * 64 + l) * 8;
                bf16x8s s6 = *(const bf16x8s*)&whp[sb + 6 * 64 * 8];
                bf16x8s s7 = *(const bf16x8s*)&whp[sb + 7 * 64 * 8];
                bf16x8s c0 = *(const bf16x8s*)&whc[((nt * 2 + 0) * 64 + l) * 8];
                bf16x8s c1 = *(const bf16x8s*)&whc[((nt * 2 + 1) * 64 + l) * 8];
                y[p][g] = __builtin_amdgcn_mfma_f32_16x16x32_bf16(a[2], wreg[p][g][0], y[p][g], 0, 0, 0);
                y[p][g] = __builtin_amdgcn_mfma_f32_16x16x32_bf16(a[3], wreg[p][g][1], y[p][g], 0, 0, 0);
                y[p][g] = __builtin_amdgcn_mfma_f32_16x16x32_bf16(a[4], wreg[p][g][2], y[p][g], 0, 0, 0);
                y[p][g] = __builtin_amdgcn_mfma_f32_16x16x32_bf16(a[5], wreg[p][g][3], y[p][g], 0, 0, 0);
                y[p][g] = __builtin_amdgcn_mfma_f32_16x16x32_bf16(a[0], c0, y[p][g], 0, 0, 0);
                y[p][g] = __builtin_amdgcn_mfma_f32_16x16x32_bf16(a[1], c1, y[p][g], 0, 0, 0);
                y[p][g] = __builtin_amdgcn_mfma_f32_16x16x32_bf16(a[6], s6, y[p][g], 0, 0, 0);
                y[p][g] = __builtin_amdgcn_mfma_f32_16x16x32_bf16(a[7], s7, y[p][g], 0, 0, 0);
            }
        }

#pragma unroll
        for (int p = 0; p < 2; ++p) {
            const int j = w * 32 + p * 16 + cl;
#pragma unroll
            for (int r = 0; r < 4; ++r) {
                float iv = sigm(y[p][0][r]);
                float fv = sigm(y[p][1][r]);
                float gv = ftanh(y[p][2][r]);
                float ov = sigm(y[p][3][r]);
                float c = fmaf(fv, creg[p][r], iv * gv);
                creg[p][r] = c;
                float hv = ov * ftanh(c);
                short hvb = f2bf(hv);
                int b = rowq * 4 + r;
                hbw[b * LDA_H + j] = hvb;
                hs[((size_t)(bbase + b) * T_ + t) * H_ + j] = hvb;
            }
        }
        __syncthreads();
    };

    for (int t = 0; t < T_; t += 2) {
        step(t,     xwA, xwB);
        step(t + 1, xwB, xwA);
    }
}

// ---------------- MFMA flash attention ----------------
// qb,kb: bf16 [B][T][H]; vt: bf16 [B][H][T]; o: fp32 [B][T][H]
// block = 256 thr (4 waves), wave owns 16 queries; grid (4, B)
__global__ __launch_bounds__(256) void k_attn_mfma(
    const short* __restrict__ qb, const short* __restrict__ kb,
    const short* __restrict__ vt, const float* __restrict__ maskf,
    float* __restrict__ o)
{
    __shared__ __align__(16) short P_lds[4][16 * 40];
    const int tid = threadIdx.x;
    const int l = tid & 63, w = tid >> 6;
    const int cl = l & 15, qr = l >> 4;
    const int b = blockIdx.y;
    const int q0 = blockIdx.x * 64 + w * 16;
    const size_t bb = (size_t)b * 256;

    bf16x8s qf[8];
    const short* qrow = qb + (bb + q0 + cl) * 256;
#pragma unroll
    for (int ks = 0; ks < 8; ++ks)
        qf[ks] = *(const bf16x8s*)&qrow[ks * 32 + qr * 8];

    float4 mr4 = *(const float4*)&maskf[bb + q0 + qr * 4];
    float msk[4] = {mr4.x, mr4.y, mr4.z, mr4.w};

    float m[4] = {-1e30f, -1e30f, -1e30f, -1e30f};
    float ls[4] = {0.f, 0.f, 0.f, 0.f};
    f32x4 acc[16];
#pragma unroll
    for (int nt = 0; nt < 16; ++nt) acc[nt] = {0.f, 0.f, 0.f, 0.f};

    for (int kt2 = 0; kt2 < 8; ++kt2) {
        const short* krow0 = kb + (bb + kt2 * 32 + cl) * 256;
        f32x4 s0 = {0.f, 0.f, 0.f, 0.f}, s1 = {0.f, 0.f, 0.f, 0.f};
#pragma unroll
        for (int ks = 0; ks < 8; ++ks) {
            bf16x8s k0f = *(const bf16x8s*)&krow0[ks * 32 + qr * 8];
            bf16x8s k1f = *(const bf16x8s*)&krow0[16 * 256 + ks * 32 + qr * 8];
            s0 = __builtin_amdgcn_mfma_f32_16x16x32_bf16(qf[ks], k0f, s0, 0, 0, 0);
            s1 = __builtin_amdgcn_mfma_f32_16x16x32_bf16(qf[ks], k1f, s1, 0, 0, 0);
        }

#pragma unroll
        for (int r = 0; r < 4; ++r) {
            float a0 = (msk[r] != 0.f) ? s0[r] : 0.f;
            float a1 = (msk[r] != 0.f) ? s1[r] : 0.f;
            float t = fmaxf(a0, a1);
            t = fmaxf(t, __shfl_xor(t, 1));
            t = fmaxf(t, __shfl_xor(t, 2));
            t = fmaxf(t, __shfl_xor(t, 4));
            t = fmaxf(t, __shfl_xor(t, 8));
            float mnew = fmaxf(m[r], t);
            float rsc = __expf(m[r] - mnew);
            m[r] = mnew;
            float p0 = __expf(a0 - mnew);
            float p1 = __expf(a1 - mnew);
            float ps = p0 + p1;
            ps += __shfl_xor(ps, 1);
            ps += __shfl_xor(ps, 2);
            ps += __shfl_xor(ps, 4);
            ps += __shfl_xor(ps, 8);
            ls[r] = ls[r] * rsc + ps;
#pragma unroll
            for (int nt = 0; nt < 16; ++nt) acc[nt][r] *= rsc;
            P_lds[w][(qr * 4 + r) * 40 + cl] = f2bf(p0);
            P_lds[w][(qr * 4 + r) * 40 + 16 + cl] = f2bf(p1);
        }

        // A-frag: P[q=cl][key = qr*8 + i] (16x16x32, K=32 keys)
        bf16x8s pa = *(const bf16x8s*)&P_lds[w][cl * 40 + qr * 8];
        const short* vrow = vt + (bb + cl) * 256 + kt2 * 32 + qr * 8;
#pragma unroll
        for (int nt = 0; nt < 16; ++nt) {
            bf16x8s vf = *(const bf16x8s*)&vrow[(size_t)nt * 16 * 256];
            acc[nt] = __builtin_amdgcn_mfma_f32_16x16x32_bf16(pa, vf, acc[nt], 0, 0, 0);
        }
    }

    float inv[4];
#pragma unroll
    for (int r = 0; r < 4; ++r) inv[r] = 1.f / ls[r];
#pragma unroll
    for (int nt = 0; nt < 16; ++nt)
#pragma unroll
        for (int r = 0; r < 4; ++r)
            o[(bb + q0 + qr * 4 + r) * 256 + nt * 16 + cl] = acc[nt][r] * inv[r];
}

// ---------------- FC1 split-K partials ----------------
__global__ __launch_bounds__(256) void k_fc1(
    const float* __restrict__ flat, const float* __restrict__ W1, float* __restrict__ part)
{
    __shared__ __align__(16) float Wt[100][260];
    __shared__ __align__(16) float fs[2][256];
    const int kc = blockIdx.x, tid = threadIdx.x;
    for (int e = tid; e < 25600; e += 256) {
        int k = e / 100, j = e - k * 100;
        Wt[j][k] = W1[(size_t)(kc * 256 + k) * 100 + j];
    }
    __syncthreads();
    const int bh = tid / 100, j = tid - bh * 100;
    for (int bb = 0; bb < 64; ++bb) {
        for (int e = tid; e < 512; e += 256) {
            int bi = e >> 8, k = e & 255;
            fs[bi][k] = flat[(size_t)(bb * 2 + bi) * 65536 + kc * 256 + k];
        }
        __syncthreads();
        if (bh < 2) {
            float acc = 0.f;
#pragma unroll 16
            for (int k = 0; k < 256; k += 4) {
                float4 fv = *(const float4*)&fs[bh][k];
                float4 wv = *(const float4*)&Wt[j][k];
                acc = fmaf(fv.x, wv.x, fmaf(fv.y, wv.y, fmaf(fv.z, wv.z, fmaf(fv.w, wv.w, acc))));
            }
            part[(size_t)kc * 12800 + (bb * 2 + bh) * 100 + j] = acc;
        }
        __syncthreads();
    }
}

// ---------------- head ----------------
__global__ __launch_bounds__(128) void k_head(
    const float* __restrict__ part, const float* __restrict__ b1,
    const float* __restrict__ W2, const float* __restrict__ b2, float* __restrict__ out)
{
    __shared__ float h1s[100];
    __shared__ float ls[2];
    const int b = blockIdx.x, tid = threadIdx.x;
    if (tid < 100) {
        float s = 0.f;
        for (int kc = 0; kc < 256; ++kc) s += part[(size_t)kc * 12800 + b * 100 + tid];
        s += b1[tid];
        h1s[tid] = fmaxf(s, 0.f);
    }
    __syncthreads();
    if (tid < 2) {
        float lg = b2[tid];
        for (int j = 0; j < 100; ++j) lg = fmaf(h1s[j], W2[j * 2 + tid], lg);
        ls[tid] = lg;
    }
    __syncthreads();
    if (tid == 0) {
        float mm = fmaxf(ls[0], ls[1]);
        float e0 = __expf(ls[0] - mm), e1 = __expf(ls[1] - mm);
        float inv = 1.f / (e0 + e1);
        out[b * 2 + 0] = e0 * inv;
        out[b * 2 + 1] = e1 * inv;
    }
}

// ---------------- launch ----------------
extern "C" void kernel_launch(void* const* d_in, const int* in_sizes, int n_in,
                              void* d_out, int out_size, void* d_ws, size_t ws_size,
                              hipStream_t stream) {
    (void)in_sizes; (void)n_in; (void)out_size; (void)ws_size;
    const int*   tokens = (const int*)  d_in[0];
    const void*  mask   =               d_in[1];
    const float* emb    = (const float*)d_in[2];
    const float* Wi     = (const float*)d_in[3];
    const float* Wh     = (const float*)d_in[4];
    const float* b_lstm = (const float*)d_in[5];
    const float* Wq     = (const float*)d_in[6];
    const float* bq     = (const float*)d_in[7];
    const float* Wk     = (const float*)d_in[8];
    const float* bk     = (const float*)d_in[9];
    const float* Wv     = (const float*)d_in[10];
    const float* bv     = (const float*)d_in[11];
    const float* Wo     = (const float*)d_in[12];
    const float* bo     = (const float*)d_in[13];
    const float* W1     = (const float*)d_in[14];
    const float* b1     = (const float*)d_in[15];
    const float* W2     = (const float*)d_in[16];
    const float* b2     = (const float*)d_in[17];
    float* out = (float*)d_out;

    float* ws = (float*)d_ws;
    float* reg0  = ws;                        // 33,554,432 f region
    short* xwp   = (short*)reg0;              // bf16 xW frag layout (67 MB)
    float* hsb   = reg0 + 33554432;           // hs bf16 / attn fp32 region
    short* hsb16 = (short*)hsb;
    float* maskf = hsb + 8388608;
    int*   rowtok= (int*)(maskf + 32768);
    int*   flag  = rowtok + 32768;
    short* whp   = (short*)((((uintptr_t)(flag + 1)) + 255) & ~(uintptr_t)255);
    short* wip   = whp + 262144;              // 640 frags
    short* wqkvp = wip + 327680;              // 384 frags
    short* wop   = wqkvp + 196608;            // 128 frags
    float* bqkv  = (float*)(wop + 65536);     // 768 f
    // region reuse inside reg0 after LSTM (xwp dead then): units = floats from reg0
    short* qb16 = (short*)reg0;                       // [0, 4.19M f)
    short* kb16 = (short*)(reg0 + 4194304);           // [4.19M, 8.39M)
    short* vt16 = (short*)(reg0 + 8388608);           // [8.39M, 12.58M)  transposed V
    float* proj = reg0 + 12582912;                    // [12.58M, 20.97M) fp32
    float* part = reg0 + 20971520;                    // [20.97M, 24.25M)
    float* attnf = hsb;                               // fp32 over hs region

    // prep
    hipMemsetAsync(flag, 0, sizeof(int), stream);
    k_detect<<<128, 256, 0, stream>>>((const unsigned char*)mask, flag);
    k_prep<<<128, 256, 0, stream>>>(mask, tokens, flag, maskf, rowtok);

    // weight packs
    k_bpack<<<512, 64, 0, stream>>>(Wh, whp, 1024, 8, 256);
    k_bpack<<<640, 64, 0, stream>>>(Wi, wip, 1024, 10, 300);
    k_packqkv<<<384, 64, 0, stream>>>(Wq, Wk, Wv, wqkvp);
    k_bias3<<<1, 768, 0, stream>>>(bq, bk, bv, bqkv);
    k_bpack<<<128, 64, 0, stream>>>(Wo, wop, 256, 8, 256);

    // xW = gather(emb,tokens) @ Wi + b_lstm -> bf16 fragment layout
    k_gemm_mfma<true, false, 2, 10><<<256, 512, 0, stream>>>(
        emb, wip, b_lstm, xwp, nullptr, nullptr, 1024, 300, rowtok);

    // LSTM (frozen R7 structure)
    lstm_mfma<<<8, 512, 0, stream>>>(xwp, whp, hsb16);

    // fused q,k,v projection: q bf16 (pre-scaled), k bf16, v bf16 transposed
    k_gemm_mfma<false, true, 3, 8><<<256, 512, 0, stream>>>(
        hsb16, wqkvp, bqkv, qb16, kb16, vt16, 768, 256, nullptr);

    // MFMA flash attention -> fp32 attnf
    k_attn_mfma<<<dim3(4, 128), 256, 0, stream>>>(qb16, kb16, vt16, maskf, attnf);

    // output projection: proj = attn @ Wo + bo (fp32 out)
    k_gemm_mfma<false, false, 0, 8><<<256, 512, 0, stream>>>(
        attnf, wop, bo, proj, nullptr, nullptr, 256, 256, nullptr);

    // FC1 split-K partials + head
    k_fc1<<<256, 256, 0, stream>>>(proj, W1, part);
    k_head<<<128, 128, 0, stream>>>(part, b1, W2, b2, out);
}